// Round 4
// baseline (574.322 us; speedup 1.0000x reference)
//
#include <hip/hip_runtime.h>
#include <hip/hip_bf16.h>
#include <stdint.h>

#define D_IN    1408
#define D_HID   256
#define N_HEADS 32
#define BATCH   16384

#define BM 128            // rows per block
#define BN 256            // full head of hidden units
#define BK 32
#define KTILES (D_IN / BK)   // 44, exact (even -> static double-buffer parity)
#define NSEG 8               // segments per persistent block (16 blocks/head)

typedef unsigned short u16;
typedef short short8 __attribute__((ext_vector_type(8)));
typedef float f32x4 __attribute__((ext_vector_type(4)));

// All inputs and the output are float32 (reference dtypes); compute is bf16
// MFMA (absmax 7.8e-3 vs threshold 2.4e-2, verified R1-R3).
__device__ __forceinline__ u16 f2b(float f) {
  __hip_bfloat16 h = __float2bfloat16(f);
  return *(u16*)&h;
}

// async global->LDS DMA, 16B/lane; LDS dest = wave-uniform base + lane*16.
__device__ __forceinline__ void gload_lds16(const void* g, void* l) {
  __builtin_amdgcn_global_load_lds(
      (const __attribute__((address_space(1))) uint32_t*)((const uint32_t*)g),
      (__attribute__((address_space(3))) uint32_t*)((uint32_t*)l),
      16, 0, 0);
}

// ---------------------------------------------------------------------------
// Kernel 0 (fused prep): convert X f32->bf16  AND  transpose W1 -> W1T bf16.
// One launch instead of two (cuts a ~10-20us launch gap; both memory-bound).
// ---------------------------------------------------------------------------
#define CONV_BLOCKS 22528   // (BATCH*D_IN/4)/256 float4s
__global__ void prep(const float4* __restrict__ X, ushort4* __restrict__ Xb,
                     const float* __restrict__ W1, u16* __restrict__ W1T) {
  const int bid = blockIdx.x;
  const int tid = threadIdx.x;
  if (bid < CONV_BLOCKS) {
    int i = bid * 256 + tid;
    float4 v = X[i];
    ushort4 o;
    o.x = f2b(v.x); o.y = f2b(v.y); o.z = f2b(v.z); o.w = f2b(v.w);
    Xb[i] = o;
    return;
  }
  // transpose part: b = f + 22*(o + 4*h)
  __shared__ u16 tile[64][68];
  const int b  = bid - CONV_BLOCKS;
  const int f0 = (b % 22) * 64;
  const int o0 = ((b / 22) & 3) * 64;
  const int h  = b / 88;
  const int tx = tid & 63;
  const int ty = tid >> 6;          // 0..3
  const size_t ib = (size_t)h * D_IN * D_HID;
  #pragma unroll
  for (int i = ty; i < 64; i += 4)
    tile[i][tx] = f2b(W1[ib + (size_t)(f0 + i) * D_HID + o0 + tx]);
  __syncthreads();
  const size_t ob = (size_t)h * D_HID * D_IN;
  #pragma unroll
  for (int pass = 0; pass < 4; ++pass) {
    int r = pass * 16 + ty * 4 + (tx >> 4);  // 0..63
    int c = (tx & 15) * 4;                   // 0..60
    ushort4 v;
    v.x = tile[c + 0][r]; v.y = tile[c + 1][r];
    v.z = tile[c + 2][r]; v.w = tile[c + 3][r];
    *(ushort4*)&W1T[ob + (size_t)(o0 + r) * D_IN + f0 + c] = v;
  }
}

// ---------------------------------------------------------------------------
// Kernel 1: PERSISTENT 128x256 / BK=32 fused GEMM, 2 blocks/CU.
//
// R3 post-mortem: per-tile time == readsvc + MFMA + overhead exactly
// (zero overlap). Intra-block overlap is blocked by the fragment-register
// WAR hazard (reads(p+1) overwrite regs in-flight MFMAs read) and fixing it
// needs +48 VGPR we don't have at 128x64 wave tiles. This rev buys overlap
// with TLP instead (m114 mechanism: independent waves on one CU co-schedule
// MFMA and LDS/VMEM at max, not sum):
//   - per-wave output 64x64 -> acc 64 VGPR, frags 32 -> total ~120 regs;
//     __launch_bounds__(512,4) caps at 128 -> 4 waves/SIMD, 16 waves/CU,
//     TWO independent blocks per CU (LDS ~58 KB < 80).
//   - one phase per K-tile: {stage t+1 (3 DMA) | 8 ds_reads | 16 MFMA |
//     vmcnt(0) | barrier}. The per-tile drain is covered by the other
//     block's compute (blocks have independent barriers -> anti-phase).
//   - BK=32 swizzle: LDS chunk ci holds global [row=ci>>2][c=(ci&3)^
//     ((row>>1)&3)]; frag read phys chunk = quad^((l15>>1)&3) -> even
//     8 words/bank (conflict-free b128), involution both sides.
//   - persistent 512 blocks, head = f(bid) constant (b1/W2 in LDS; the
//     same-head CU-pair shares the L2-resident W1T slice); 8 segments,
//     cross-segment staging keeps the DMA queue continuously fed.
// ---------------------------------------------------------------------------
__global__ __launch_bounds__(512, 4) void mano_gemm(
    const u16* __restrict__ X,               // [16384][1408] bf16 (ws)
    const u16* __restrict__ W1T,             // [32][256][1408] bf16 (ws)
    const float* __restrict__ b1,            // [32][256] f32
    const float* __restrict__ W2,            // [32][256][3] f32
    const float* __restrict__ b2,            // [32][3] f32
    float* __restrict__ out)                 // [16384][96] f32 (d_out)
{
  __shared__ __align__(16) u16 As[2][BM * BK];   // 2 x 8 KB
  __shared__ __align__(16) u16 Bs[2][BN * BK];   // 2 x 16 KB
  __shared__ __align__(16) float scr[1536];      // 6 KB epilogue scratch
  __shared__ float b1L[256];                     // head-constant params
  __shared__ float w2L[768];
  __shared__ float b2L[3];

  const int tid  = threadIdx.x;
  const int lane = tid & 63;
  const int wid  = tid >> 6;        // 0..7
  const int quad = lane >> 4;
  const int l15  = lane & 15;
  const int wm   = wid >> 2;        // 0..1 (64-row half)
  const int wn   = wid & 3;         // 0..3 (64-col band)

  const int bid  = blockIdx.x;              // 0..511
  const int head = (bid & 7) * 4 + ((bid >> 3) & 3);   // constant per block
  const int u    = bid >> 5;                           // 0..15

  const u16* Bu = W1T + (size_t)head * D_HID * D_IN;

  // ---- head-constant params -> LDS (once) ----
  if (tid < 256) b1L[tid] = b1[head * D_HID + tid];
  for (int i = tid; i < 768; i += 512) w2L[i] = W2[(size_t)head * D_HID * 3 + i];
  if (tid < 3)  b2L[tid] = b2[head * 3 + tid];

  // staging offsets (u16 units). A: 512 chunks (1/thread); B: 1024 (2/thread).
  // LDS linear chunk ci holds global [row=ci>>2][g=(ci&3)^((row>>1)&3)].
  int aoff;
  {
    int row = tid >> 2, c = tid & 3;
    aoff = row * D_IN + (c ^ ((row >> 1) & 3)) * 8;
  }
  int boff[2];
  #pragma unroll
  for (int cc = 0; cc < 2; ++cc) {
    int ci = cc * 512 + tid;
    int row = ci >> 2, c = ci & 3;
    boff[cc] = row * D_IN + (c ^ ((row >> 1) & 3)) * 8;
  }

  // frag read: row r = w*64 + f*16 + l15; phys chunk p = quad ^ ((r>>1)&3);
  // (r>>1)&3 == (l15>>1)&3 since w*64, f*16 are multiples of 16.
  const int p16 = (quad ^ ((l15 >> 1) & 3)) * 16;   // byte offset of chunk
  const int abase = (wm * 64 + l15) * 64 + p16;     // + mf*1024
  const int bbase = (wn * 64 + l15) * 64 + p16;     // + nf*1024

#define STG(BI, AP, BP) do {                                                   \
    gload_lds16((AP) + aoff, &As[BI][wid * 512]);                              \
    _Pragma("unroll")                                                          \
    for (int cc = 0; cc < 2; ++cc)                                             \
      gload_lds16((BP) + boff[cc], &Bs[BI][(cc * 512 + wid * 64) * 8]);        \
  } while (0)

  f32x4 acc[4][4];
  #pragma unroll
  for (int i = 0; i < 4; ++i)
    #pragma unroll
    for (int j = 0; j < 4; ++j)
      acc[i][j] = f32x4{0.f, 0.f, 0.f, 0.f};

  short8 a[4], b[4];

  // One K-tile: stage t+1 into other buf; read 8 frags; 16 MFMA; drain; bar.
  // The other resident block computes through our drain (TLP overlap).
#define TILE(BI, AP, BP, SK) do {                                              \
    if (!(SK)) STG((BI) ^ 1, AP, BP);                                          \
    _Pragma("unroll") for (int mf = 0; mf < 4; ++mf)                           \
      a[mf] = *(const short8*)((const char*)&As[BI][0] + abase + mf * 1024);   \
    _Pragma("unroll") for (int nf = 0; nf < 4; ++nf)                           \
      b[nf] = *(const short8*)((const char*)&Bs[BI][0] + bbase + nf * 1024);   \
    __builtin_amdgcn_s_setprio(1);                                             \
    _Pragma("unroll") for (int mf = 0; mf < 4; ++mf)                           \
      _Pragma("unroll") for (int nf = 0; nf < 4; ++nf)                         \
        acc[mf][nf] = __builtin_amdgcn_mfma_f32_16x16x32_bf16(                 \
            a[mf], b[nf], acc[mf][nf], 0, 0, 0);                               \
    __builtin_amdgcn_s_setprio(0);                                             \
    asm volatile("s_waitcnt vmcnt(0)" ::: "memory");                           \
    __builtin_amdgcn_s_barrier();                                              \
  } while (0)

  // ---- prologue: stage tile 0 of segment 0 into buf0 ----
  {
    const u16* A0 = X + (size_t)(u * BM) * D_IN;
    STG(0, A0, Bu);
    asm volatile("s_waitcnt lgkmcnt(0)" ::: "memory");  // param ds_writes done
    asm volatile("s_waitcnt vmcnt(0)" ::: "memory");
    __builtin_amdgcn_s_barrier();
  }

  #pragma unroll 1
  for (int g = 0; g < NSEG; ++g) {
    const u16* AuC = X + (size_t)((g * 16 + u) * BM) * D_IN;
    const u16* AuN = AuC + (size_t)(16 * BM) * D_IN;   // next segment (g<7)
    const bool lastseg = (g == NSEG - 1);

    #pragma unroll 1
    for (int j = 0; j < KTILES / 2; ++j) {
      const int kt1 = 2 * j + 1;          // stage target of TILE0 (in-seg)
      const int kt2 = 2 * j + 2;          // stage target of TILE1 (may wrap)
      const bool wrap = (kt2 >= KTILES);
      const int k2m  = wrap ? 0 : kt2;
      const u16* Ap1 = AuC + kt1 * BK;
      const u16* Bp1 = Bu + kt1 * BK;
      const u16* Ap2 = (wrap ? AuN : AuC) + k2m * BK;
      const u16* Bp2 = Bu + k2m * BK;
      const bool sk2 = lastseg && wrap;   // nothing after the last segment

      TILE(0, Ap1, Bp1, false);
      TILE(1, Ap2, Bp2, sk2);
    }

    // ---- fused epilogue (per segment): relu(acc+b1).W2, 4-wave combine ----
    // acc[mf][nf] elem (quad,r): row = wm*64+mf*16+quad*4+r (0..127),
    //                            col = wn*64+nf*16+l15
    {
      float b1v[4], w2v[4][3];
      #pragma unroll
      for (int nf = 0; nf < 4; ++nf) {
        int col = wn * 64 + nf * 16 + l15;
        b1v[nf] = b1L[col];
        #pragma unroll
        for (int p = 0; p < 3; ++p) w2v[nf][p] = w2L[col * 3 + p];
      }
      const int m0 = (g * 16 + u) * BM;

      #pragma unroll
      for (int mf = 0; mf < 4; ++mf) {
        float ps[4][3];
        #pragma unroll
        for (int r = 0; r < 4; ++r)
          #pragma unroll
          for (int p = 0; p < 3; ++p) ps[r][p] = 0.f;

        #pragma unroll
        for (int nf = 0; nf < 4; ++nf)
          #pragma unroll
          for (int r = 0; r < 4; ++r) {
            float h = acc[mf][nf][r] + b1v[nf];
            h = h > 0.f ? h : 0.f;
            #pragma unroll
            for (int p = 0; p < 3; ++p)
              ps[r][p] = fmaf(h, w2v[nf][p], ps[r][p]);
          }

        // sum over the 16 column-lanes (xor on low 4 lane bits stays in-quad)
        #pragma unroll
        for (int mask = 1; mask < 16; mask <<= 1)
          #pragma unroll
          for (int r = 0; r < 4; ++r)
            #pragma unroll
            for (int p = 0; p < 3; ++p)
              ps[r][p] += __shfl_xor(ps[r][p], mask, 64);

        if (l15 == 0) {
          int row = wm * 64 + mf * 16 + quad * 4;          // +r below
          #pragma unroll
          for (int r = 0; r < 4; ++r)
            #pragma unroll
            for (int p = 0; p < 3; ++p)
              scr[((row + r) * 3 + p) * 4 + wn] = ps[r][p];
        }
      }
      // raw barrier (NOT __syncthreads: in-flight DMA of next seg's tile 0/1
      // must not be drained -- it targets As/Bs, disjoint from scr)
      asm volatile("s_waitcnt lgkmcnt(0)" ::: "memory");
      __builtin_amdgcn_s_barrier();

      for (int i = tid; i < BM * 3; i += 512) {
        int row = i / 3, p = i - row * 3;
        float v = scr[i * 4 + 0] + scr[i * 4 + 1] + scr[i * 4 + 2]
                + scr[i * 4 + 3] + b2L[p];
        out[(size_t)(m0 + row) * (N_HEADS * 3) + head * 3 + p] = v;
      }

      #pragma unroll
      for (int i = 0; i < 4; ++i)
        #pragma unroll
        for (int jj = 0; jj < 4; ++jj)
          acc[i][jj] = f32x4{0.f, 0.f, 0.f, 0.f};
      // scr reads complete before the next epilogue's writes (44 tile
      // barriers away); next TILE reads As/Bs, disjoint from scr.
    }
  }

#undef STG
#undef TILE
}

extern "C" void kernel_launch(void* const* d_in, const int* in_sizes, int n_in,
                              void* d_out, int out_size, void* d_ws, size_t ws_size,
                              hipStream_t stream) {
  const float* X  = (const float*)d_in[0];
  const float* W1 = (const float*)d_in[1];
  const float* b1 = (const float*)d_in[2];
  const float* W2 = (const float*)d_in[3];
  const float* b2 = (const float*)d_in[4];

  // ws: Xb 46,137,344 | W1T 23,068,672  = 69,206,016 B (proven fits)
  u16* Xb  = (u16*)d_ws;
  u16* W1T = (u16*)((char*)d_ws + (size_t)BATCH * D_IN * 2);

  prep<<<CONV_BLOCKS + (D_IN / 64) * (D_HID / 64) * N_HEADS, 256, 0, stream>>>(
      (const float4*)X, (ushort4*)Xb, W1, W1T);

  mano_gemm<<<dim3(512), 512, 0, stream>>>(
      Xb, W1T, b1, W2, b2, (float*)d_out);
}